// Round 2
// baseline (3457.973 us; speedup 1.0000x reference)
//
#include <hip/hip_runtime.h>

#define EPSV 1e-5f

__device__ __forceinline__ float sigmoidf_(float x) {
  return 1.f / (1.f + __expf(-x));
}

// ---------------------------------------------------------------------------
// Precompute W_comb[i][m][k] = sum_j fusion_W[p][m][d*64+j] * out_W[i][j][k]
// i = phase*2+dir, p = i>>1, d = i&1.  Fuses out_proj into fusion matmul.
// ---------------------------------------------------------------------------
__global__ __launch_bounds__(256) void precomp_wc(
    const float* __restrict__ fW,   // (2,64,128) f32
    const float* __restrict__ oW,   // (4,64,128) f32
    float* __restrict__ Wc)         // (4,64,128) f32
{
  const int bi = blockIdx.x;
  const int i = bi >> 3, mg = bi & 7;
  const int m = (mg << 3) + (threadIdx.x >> 5);
  const int k0 = (threadIdx.x & 31) << 2;
  const int p = i >> 1, d = i & 1;
  const float* fr = fW + p * 8192 + m * 128 + d * 64;
  const float* orow = oW + i * 8192 + k0;
  float a0 = 0.f, a1 = 0.f, a2 = 0.f, a3 = 0.f;
  for (int j = 0; j < 64; ++j) {
    const float f = fr[j];
    const float4 o4 = *(const float4*)(orow + j * 128);
    a0 += f * o4.x; a1 += f * o4.y;
    a2 += f * o4.z; a3 += f * o4.w;
  }
  float* out = Wc + i * 8192 + m * 128 + k0;
  out[0] = a0; out[1] = a1; out[2] = a2; out[3] = a3;
}

// ---------------------------------------------------------------------------
// One block = one sequence (512 sequences/phase). Both directions fused.
// Chunked (CH=16) pipeline: LN -> in_proj -> conv -> scan -> gate/rmsnorm ->
// W_comb matmul -> store (dir0 store, dir1 atomicAdd).
// LDS total = 56 KB -> 2 blocks/CU.
// ---------------------------------------------------------------------------
__global__ __launch_bounds__(256, 2) void mamba_phase(
    const float* __restrict__ xin,   // f32 original x (4,64,128,128)
    const float* __restrict__ srcf,  // f32 src (phase1: xbuf)
    float* __restrict__ dst,         // f32 accumulation target
    const float* __restrict__ WpA,   // in_proj_W (4,386,64)
    const float* __restrict__ cwA,   // conv_W (4,256,4)
    const float* __restrict__ cbA,   // conv_b (4,256)
    const float* __restrict__ dtbA,  // dt_bias (4,2)
    const float* __restrict__ AlA,   // A_log (4,2)
    const float* __restrict__ DpA,   // D_param (4,2)
    const float* __restrict__ nwA,   // norm_w (4,128)
    const float* __restrict__ lnwA,  // ln_w (2,64)
    const float* __restrict__ lnbA,  // ln_b (2,64)
    const float* __restrict__ fbA,   // fusion_b (2,64)
    const float* __restrict__ WcA,   // (4,64,128) f32
    int phase)
{
  __shared__ float sU[16][68];   // LN'd input chunk (pad 68: bank spread)
  __shared__ float sZ[16][388];  // zxbcdt chunk
  __shared__ float sX[16][256];  // conv+silu output (x|B|C)
  __shared__ float sY[16][132];  // scan y then g_norm
  __shared__ float sH[3][256];   // conv history (raw xBC)
  __shared__ float sDt[16][2];
  __shared__ float sDa[16][2];

  const int tid = threadIdx.x;
  const int s = blockIdx.x;
  const int b = s >> 7;
  const int q = s & 127;
  const size_t base_b = (size_t)b * (64 * 128 * 128);
  const int pos_stride = phase ? 128 : 1;   // pos = t (phase1) or f (phase0)
  const int fixed_off = phase ? q : (q << 7);

  for (int dir = 0; dir < 2; ++dir) {
    const int ip = phase * 2 + dir;
    const float* Wp = WpA + (size_t)ip * 24704;
    const float* Wc = WcA + ip * 8192;
    const float dtb0 = dtbA[ip * 2 + 0], dtb1 = dtbA[ip * 2 + 1];
    const float nA0 = -__expf(AlA[ip * 2 + 0]);
    const float nA1 = -__expf(AlA[ip * 2 + 1]);
    const float Dp0 = DpA[ip * 2 + 0], Dp1 = DpA[ip * 2 + 1];

    float S[32];                 // per-thread scan state (half a state row)
    #pragma unroll
    for (int i = 0; i < 32; ++i) S[i] = 0.f;

    sH[0][tid] = 0.f; sH[1][tid] = 0.f; sH[2][tid] = 0.f;
    __syncthreads();

    for (int ck = 0; ck < 8; ++ck) {
      // ---- 1. load x chunk (raw) ----
      {
        const int pl = tid & 15, cg = tid >> 4;
        const int st = (ck << 4) + pl;
        const int rp = dir ? (127 - st) : st;
        const size_t pbase = base_b + fixed_off + (size_t)rp * pos_stride;
        #pragma unroll
        for (int j = 0; j < 4; ++j) {
          const int c = (cg << 2) + j;
          const size_t idx = pbase + (size_t)c * 16384;
          sU[pl][c] = phase ? srcf[idx] : xin[idx];
        }
      }
      __syncthreads();
      // ---- 2. layernorm over 64 channels ----
      {
        const int pl = tid >> 4, c0 = (tid & 15) << 2;
        const float v0 = sU[pl][c0 + 0], v1 = sU[pl][c0 + 1];
        const float v2 = sU[pl][c0 + 2], v3 = sU[pl][c0 + 3];
        float sm = v0 + v1 + v2 + v3;
        float s2 = v0 * v0 + v1 * v1 + v2 * v2 + v3 * v3;
        sm += __shfl_xor(sm, 1); s2 += __shfl_xor(s2, 1);
        sm += __shfl_xor(sm, 2); s2 += __shfl_xor(s2, 2);
        sm += __shfl_xor(sm, 4); s2 += __shfl_xor(s2, 4);
        sm += __shfl_xor(sm, 8); s2 += __shfl_xor(s2, 8);
        const float mean = sm * (1.f / 64.f);
        const float var = s2 * (1.f / 64.f) - mean * mean;
        const float inv = rsqrtf(var + EPSV);
        const int lb = phase * 64 + c0;
        sU[pl][c0 + 0] = (v0 - mean) * inv * lnwA[lb + 0] + lnbA[lb + 0];
        sU[pl][c0 + 1] = (v1 - mean) * inv * lnwA[lb + 1] + lnbA[lb + 1];
        sU[pl][c0 + 2] = (v2 - mean) * inv * lnwA[lb + 2] + lnbA[lb + 2];
        sU[pl][c0 + 3] = (v3 - mean) * inv * lnwA[lb + 3] + lnbA[lb + 3];
      }
      __syncthreads();
      // ---- 3. in_proj: sZ[lt][o] = u[lt] . Wp[o] ----
      for (int o = tid; o < 386; o += 256) {
        const float4* wp4 = (const float4*)(Wp + ((size_t)o << 6));
        float w[64];
        #pragma unroll
        for (int i = 0; i < 16; ++i) {
          const float4 a = wp4[i];
          w[i * 4 + 0] = a.x; w[i * 4 + 1] = a.y;
          w[i * 4 + 2] = a.z; w[i * 4 + 3] = a.w;
        }
        for (int lt = 0; lt < 16; ++lt) {
          const float4* ur = (const float4*)(&sU[lt][0]);
          float acc = 0.f;
          #pragma unroll
          for (int i = 0; i < 16; ++i) {
            const float4 uv = ur[i];
            acc += w[i * 4 + 0] * uv.x + w[i * 4 + 1] * uv.y +
                   w[i * 4 + 2] * uv.z + w[i * 4 + 3] * uv.w;
          }
          sZ[lt][o] = acc;
        }
      }
      __syncthreads();
      // ---- 4. dt / dA (32 threads) ----
      if (tid < 32) {
        const int lt = tid >> 1, hh = tid & 1;
        const float v = sZ[lt][384 + hh] + (hh ? dtb1 : dtb0);
        const float dt = (v > 20.f) ? v : log1pf(__expf(v));
        sDt[lt][hh] = dt;
        sDa[lt][hh] = __expf(dt * (hh ? nA1 : nA0));
      }
      // ---- 5. conv(4, causal) + silu; rolling regs + history ----
      {
        const int c = tid;
        const float4 cw4 = *(const float4*)(cwA + ip * 1024 + (c << 2));
        const float w0 = cw4.x, w1 = cw4.y, w2 = cw4.z, w3 = cw4.w;
        const float bias = cbA[ip * 256 + c];
        float a0 = sH[0][c], a1 = sH[1][c], a2 = sH[2][c];
        #pragma unroll
        for (int lt = 0; lt < 16; ++lt) {
          const float a3 = sZ[lt][128 + c];
          const float acc = bias + a0 * w0 + a1 * w1 + a2 * w2 + a3 * w3;
          sX[lt][c] = acc * sigmoidf_(acc);
          a0 = a1; a1 = a2; a2 = a3;
        }
        sH[0][c] = a0; sH[1][c] = a1; sH[2][c] = a2;
      }
      __syncthreads();
      // ---- 6. selective scan: 128 rows x 2 half-threads, 32 states each ----
      {
        const int row = tid >> 1, half = tid & 1;
        const int hh = row >> 6, p = row & 63;
        const int xoff = (hh << 6) + p;
        const int boff = 128 + (half << 5);
        for (int lt = 0; lt < 16; ++lt) {
          const float dAt = sDa[lt][hh];
          const float dtx = sDt[lt][hh] * sX[lt][xoff];
          const float4* Bp = (const float4*)(&sX[lt][boff]);
          const float4* Cp = (const float4*)(&sX[lt][boff + 64]);
          float yp = 0.f;
          #pragma unroll
          for (int i = 0; i < 8; ++i) {
            const float4 Bv = Bp[i], Cv = Cp[i];
            S[i * 4 + 0] = S[i * 4 + 0] * dAt + dtx * Bv.x; yp += S[i * 4 + 0] * Cv.x;
            S[i * 4 + 1] = S[i * 4 + 1] * dAt + dtx * Bv.y; yp += S[i * 4 + 1] * Cv.y;
            S[i * 4 + 2] = S[i * 4 + 2] * dAt + dtx * Bv.z; yp += S[i * 4 + 2] * Cv.z;
            S[i * 4 + 3] = S[i * 4 + 3] * dAt + dtx * Bv.w; yp += S[i * 4 + 3] * Cv.w;
          }
          yp += __shfl_xor(yp, 1);
          sY[lt][xoff] = yp;   // both halves write same value
        }
      }
      __syncthreads();
      // ---- 7. gate with silu(z) + rmsnorm ----
      {
        const int lt = tid >> 4, c0 = (tid & 15) << 3;
        float g[8];
        float ssq = 0.f;
        #pragma unroll
        for (int j = 0; j < 8; ++j) {
          const int k = c0 + j;
          const float z = sZ[lt][k];
          const float dp = (k >> 6) ? Dp1 : Dp0;
          const float val = (sY[lt][k] + dp * sX[lt][k]) * (z * sigmoidf_(z));
          g[j] = val; ssq += val * val;
        }
        ssq += __shfl_xor(ssq, 1);
        ssq += __shfl_xor(ssq, 2);
        ssq += __shfl_xor(ssq, 4);
        ssq += __shfl_xor(ssq, 8);
        const float scale = rsqrtf(ssq * (1.f / 128.f) + EPSV);
        #pragma unroll
        for (int j = 0; j < 8; ++j)
          sY[lt][c0 + j] = g[j] * scale * nwA[ip * 128 + c0 + j];
      }
      __syncthreads();
      // ---- 8. fused out_proj+fusion matmul, store/accumulate ----
      {
        const int lt = tid >> 4, mb = tid & 15;
        const int st = (ck << 4) + lt;
        const int rp = dir ? (127 - st) : st;
        const size_t obase = base_b + fixed_off + (size_t)rp * pos_stride;
        const float4* gy = (const float4*)(&sY[lt][0]);
        #pragma unroll
        for (int j = 0; j < 4; ++j) {
          const int m = mb + (j << 4);
          const float4* wc = (const float4*)(Wc + (m << 7));
          float acc = 0.f;
          #pragma unroll
          for (int i = 0; i < 32; ++i) {
            const float4 wv = wc[i], gv = gy[i];
            acc += wv.x * gv.x + wv.y * gv.y + wv.z * gv.z + wv.w * gv.w;
          }
          const size_t e = obase + (size_t)m * 16384;
          if (dir == 0) {
            const float resid = (phase ? srcf[e] : xin[e]) + fbA[phase * 64 + m];
            dst[e] = resid + acc;         // single writer per element
          } else {
            atomicAdd(&dst[e], acc);      // L2 atomic: no L1 staleness
          }
        }
      }
      __syncthreads();
    }
    __syncthreads();
  }
}

extern "C" void kernel_launch(void* const* d_in, const int* in_sizes, int n_in,
                              void* d_out, int out_size, void* d_ws, size_t ws_size,
                              hipStream_t stream) {
  const float* x   = (const float*)d_in[0];
  const float* Wp  = (const float*)d_in[1];
  const float* cw  = (const float*)d_in[2];
  const float* cb  = (const float*)d_in[3];
  const float* dtb = (const float*)d_in[4];
  const float* Al  = (const float*)d_in[5];
  const float* Dp  = (const float*)d_in[6];
  const float* nw  = (const float*)d_in[7];
  const float* oW  = (const float*)d_in[8];
  const float* fW  = (const float*)d_in[9];
  const float* fb  = (const float*)d_in[10];
  const float* lnw = (const float*)d_in[11];
  const float* lnb = (const float*)d_in[12];

  float* ws   = (float*)d_ws;
  float* Wc   = ws;                  // 32768 floats
  float* xbuf = ws + 32768;          // 4194304 floats (x after phase 0)
  float* outf = (float*)d_out;       // final f32 output, written directly

  precomp_wc<<<32, 256, 0, stream>>>(fW, oW, Wc);
  mamba_phase<<<512, 256, 0, stream>>>(x, xbuf, xbuf, Wp, cw, cb, dtb, Al, Dp,
                                       nw, lnw, lnb, fb, Wc, 0);
  mamba_phase<<<512, 256, 0, stream>>>(x, xbuf, outf, Wp, cw, cb, dtb, Al, Dp,
                                       nw, lnw, lnb, fb, Wc, 1);
}